// Round 8
// baseline (554.234 us; speedup 1.0000x reference)
//
#include <hip/hip_runtime.h>

typedef unsigned short u16;
typedef unsigned int u32;
typedef __bf16 bf16x8 __attribute__((ext_vector_type(8)));
typedef float f32x4 __attribute__((ext_vector_type(4)));

__device__ __forceinline__ u16 f2b(float f) {
  u32 u = __builtin_bit_cast(u32, f);
  u32 r = (u + 0x7fffu + ((u >> 16) & 1u)) >> 16;  // RNE
  return (u16)r;
}
__device__ __forceinline__ bf16x8 ld_frag(const u16* p) {
  uint4 v = *(const uint4*)p;
  return __builtin_bit_cast(bf16x8, v);
}
__device__ __forceinline__ void async_lds16(const u16* g, u16* lds) {
  __builtin_amdgcn_global_load_lds(
      (const __attribute__((address_space(1))) void*)g,
      (__attribute__((address_space(3))) void*)lds, 16, 0, 0);
}
// wait lgkmcnt(0) only (vmcnt=63, expcnt=7 untouched)
__device__ __forceinline__ void wait_lds() { __builtin_amdgcn_s_waitcnt(0xc07f); }

// ---------------- fp32 -> bf16 bulk convert (x) ----------------
__global__ __launch_bounds__(256) void convert_f32_bf16(const float* __restrict__ in,
                                                        u16* __restrict__ out) {
  long i = ((long)blockIdx.x * 256 + threadIdx.x) * 8;
  float4 a = *(const float4*)(in + i);
  float4 b = *(const float4*)(in + i + 4);
  union { uint4 v; u16 e[8]; } u;
  u.e[0] = f2b(a.x); u.e[1] = f2b(a.y); u.e[2] = f2b(a.z); u.e[3] = f2b(a.w);
  u.e[4] = f2b(b.x); u.e[5] = f2b(b.y); u.e[6] = f2b(b.z); u.e[7] = f2b(b.w);
  *(uint4*)(out + i) = u.v;
}

// ---------------- weight transpose+convert: W_f32[K][N] -> Wt_bf16[N][K] ----------------
__global__ __launch_bounds__(256) void transpose_w(const float* __restrict__ W,
                                                   u16* __restrict__ Wt,
                                                   int K, int N) {
  __shared__ alignas(16) u16 T[64][80];
  const int n0 = blockIdx.x * 64, k0 = blockIdx.y * 64;
  const int t = threadIdx.x;
  {
    int kk = t >> 3, c = t & 7;
#pragma unroll
    for (int rr = 0; rr < 2; ++rr) {
      int kr = kk + rr * 32;
      const float* src = W + (long)(k0 + kr) * N + n0 + c * 8;
      float4 a = *(const float4*)src;
      float4 b = *(const float4*)(src + 4);
      u16* dst = &T[kr][c * 8];
      dst[0] = f2b(a.x); dst[1] = f2b(a.y); dst[2] = f2b(a.z); dst[3] = f2b(a.w);
      dst[4] = f2b(b.x); dst[5] = f2b(b.y); dst[6] = f2b(b.z); dst[7] = f2b(b.w);
    }
  }
  __syncthreads();
  {
    int nn = t >> 3, kc = t & 7;
#pragma unroll
    for (int rr = 0; rr < 2; ++rr) {
      int nr = nn + rr * 32;
      union { uint4 v; u16 e[8]; } u;
#pragma unroll
      for (int i = 0; i < 8; ++i) u.e[i] = T[kc * 8 + i][nr];
      *(uint4*)(Wt + (long)(n0 + nr) * K + k0 + kc * 8) = u.v;
    }
  }
}

// ---------------- phased GEMM with COUNTED vmcnt (T3+T4): C = A*Bt^T + bias ----------------
// BM=BN=256, BK=64; 512 thr = 8 waves (2M x 4N), wave tile 128x64, acc[8][4].
// LDS: dbuf-2 K-tile slots, 64 KiB each (A [256][64] + B [256][64]) = 128 KiB.
// Stage units (8 KB, one gload_lds each): u0=A rows0-63, u1=A 64-127, u2=A 128-191,
// u3=A 192-255, u4..u7 = B quarters 0..3. Per-wave reads touch only units
// {2wm (ph0 A-lo), 4+wn (ph0/ph1 B), 2wm+1 (ph2 A-hi)}.
// ISSUE ORDER for tile t+1 (during tile t): ph0: u0,u2,u4,u5; ph1: u6,u7,u1,u3.
// COUNTED WAITS (never drain to 0 mid-loop):
//  - tile gate: vmcnt(2) -> first 6 issued units of tile t (u0,u2,u4..u7) landed;
//    covers all ph0/ph1 reads. The 2 newest (u1,u3 = A-hi) stay in flight.
//  - end of ph1: vmcnt(8) -> allows the 8 just-issued t+1 stages to fly while
//    forcing tile t's last 2 (A-hi) to land before ph2 reads. (tail: vmcnt(0))
// So every load is waited >=2 phases after issue; oldest at the gate is 7 phases old.
// NOTE: s_waitcnt builtin takes a LITERAL constant only -- select via uniform if/else.
// Race-freedom (dbuf-2): stages of t+1 (slot (t+1)&1) are issued after gate barrier
// G_t; last reads of that slot were in tile t-1, completed (lgkmcnt before their
// MFMAs) before G_t. Region completeness: all waves issue stages in the same order,
// so vmcnt(N)+barrier => first (8-N) units complete across all wave-slices.
// Phases: ph0 {12 ds_read (A-lo,B-lo) | 4 stages | bar | MFMA mlo*nlo | bar}
//         ph1 {4 ds_read (B-hi) | 4 stages | bar | MFMA mlo*nhi | vmcnt(8) bar}
//         ph2 {8 ds_read (A-hi) | bar | MFMA mhi*nhi | bar}
//         ph3 {MFMA mhi*nlo (b0 held in regs since ph0)}
// Swizzle (128B rows, 8x16B chunks): chunk c at position c^(row&7); linear LDS dest +
// inverse-swizzled global source (chunk (tid&7)^((tid>>3)&7)); reads use matching XOR.
template <bool OUT_F32>
__global__ __launch_bounds__(512, 2) void gemm_pipe(const u16* __restrict__ A,
                                                    const u16* __restrict__ Bt,
                                                    const float* __restrict__ bias,
                                                    void* __restrict__ Cv,
                                                    int M, int N, int K) {
  __shared__ alignas(16) u16 lds[2 * 32768];  // slot s: A @ s*32768, B @ s*32768+16384
  const int tid = threadIdx.x;
  const int lane = tid & 63, wave = tid >> 6;
  const int quad = lane >> 4, ln = lane & 15;
  const int wm = wave >> 2, wn = wave & 3;  // per-wave 128x64 tile

  // XCD-aware bijective swizzle (nwg % 8 == 0 for both launches)
  const int nwg = gridDim.x;
  const int bid = blockIdx.x;
  const int wg = (bid & 7) * (nwg >> 3) + (bid >> 3);
  const int ntn = N >> 8;
  const int tn = wg % ntn, tm = wg / ntn;
  const long m0 = (long)tm * 256;
  const long n0 = (long)tn * 256;

  // staging source: thread covers row (tid>>3) of a 64-row unit, holding the
  // inverse-swizzled chunk (tid&7)^((tid>>3)&7). One gload_lds = 512thr x 16B = 64 rows.
  const int strow = tid >> 3;
  const int gsw = ((tid & 7) ^ (strow & 7)) * 8;
  const u16* gA = A + (m0 + strow) * (long)K + gsw;
  const u16* gB = Bt + (n0 + strow) * (long)K + gsw;

  const int KT = K >> 6;

  // u: 0..3 = A 64-row units, 4..7 = B quarters (64 rows each)
  auto stageU = [&](int t, int u) {
    int off = (u < 4) ? u * 4096 : 16384 + (u - 4) * 4096;
    u16* d = &lds[(t & 1) * 32768 + off + wave * 512];
    int grow = (u < 4) ? u * 64 : (u - 4) * 64;
    const u16* g = (u < 4) ? gA : gB;
    async_lds16(g + (long)grow * K + (long)t * 64, d);
  };

  auto ldA = [&](int t, int mt, int ks) {
    int row = wm * 128 + mt * 16 + ln;
    int pos = (ks * 4 + quad) ^ (row & 7);
    return ld_frag(&lds[(t & 1) * 32768 + row * 64 + pos * 8]);
  };
  auto ldB = [&](int t, int nt, int ks) {
    int row = wn * 64 + nt * 16 + ln;
    int pos = (ks * 4 + quad) ^ (row & 7);
    return ld_frag(&lds[(t & 1) * 32768 + 16384 + row * 64 + pos * 8]);
  };

  f32x4 zero = {0.f, 0.f, 0.f, 0.f};
  f32x4 acc[8][4];
#pragma unroll
  for (int i = 0; i < 8; ++i)
#pragma unroll
    for (int j = 0; j < 4; ++j) acc[i][j] = zero;

  // prologue: stage tile 0 in ISSUE ORDER (first 6 = gate set, last 2 = A-hi)
  stageU(0, 0); stageU(0, 2); stageU(0, 4); stageU(0, 5);
  stageU(0, 6); stageU(0, 7); stageU(0, 1); stageU(0, 3);

  for (int t = 0; t < KT; ++t) {
    const bool pf = (t + 1 < KT);
    // ---- tile gate: first-6 units of tile t landed (A-hi may still fly) ----
    __builtin_amdgcn_s_waitcnt(0x0f72);  // vmcnt(2)
    __builtin_amdgcn_s_barrier();

    bf16x8 a[8], b0[4], b1[4];
    // ---- phase 0: A-lo + B-lo reads; issue stages u0,u2,u4,u5(t+1); MFMA mlo*nlo ----
#pragma unroll
    for (int mt = 0; mt < 4; ++mt)
#pragma unroll
      for (int ks = 0; ks < 2; ++ks) a[mt * 2 + ks] = ldA(t, mt, ks);
#pragma unroll
    for (int nt = 0; nt < 2; ++nt)
#pragma unroll
      for (int ks = 0; ks < 2; ++ks) b0[nt * 2 + ks] = ldB(t, nt, ks);
    if (pf) { stageU(t + 1, 0); stageU(t + 1, 2); stageU(t + 1, 4); stageU(t + 1, 5); }
    __builtin_amdgcn_s_barrier();
    wait_lds();
    __builtin_amdgcn_s_setprio(1);
#pragma unroll
    for (int mt = 0; mt < 4; ++mt)
#pragma unroll
      for (int nt = 0; nt < 2; ++nt)
#pragma unroll
        for (int ks = 0; ks < 2; ++ks)
          acc[mt][nt] = __builtin_amdgcn_mfma_f32_16x16x32_bf16(a[mt * 2 + ks], b0[nt * 2 + ks], acc[mt][nt], 0, 0, 0);
    __builtin_amdgcn_s_setprio(0);
    __builtin_amdgcn_s_barrier();
    // ---- phase 1: B-hi reads; issue stages u6,u7,u1,u3(t+1); MFMA mlo*nhi ----
#pragma unroll
    for (int nt = 0; nt < 2; ++nt)
#pragma unroll
      for (int ks = 0; ks < 2; ++ks) b1[nt * 2 + ks] = ldB(t, nt + 2, ks);
    if (pf) { stageU(t + 1, 6); stageU(t + 1, 7); stageU(t + 1, 1); stageU(t + 1, 3); }
    __builtin_amdgcn_s_barrier();
    wait_lds();
    __builtin_amdgcn_s_setprio(1);
#pragma unroll
    for (int mt = 0; mt < 4; ++mt)
#pragma unroll
      for (int nt = 0; nt < 2; ++nt)
#pragma unroll
        for (int ks = 0; ks < 2; ++ks)
          acc[mt][nt + 2] = __builtin_amdgcn_mfma_f32_16x16x32_bf16(a[mt * 2 + ks], b1[nt * 2 + ks], acc[mt][nt + 2], 0, 0, 0);
    __builtin_amdgcn_s_setprio(0);
    // counted gate for ph2's A-hi: tile t's last-2 land; t+1's 8 stay in flight
    // (literal-constant waitcnt selected by wave-uniform branch)
    if (pf) __builtin_amdgcn_s_waitcnt(0x0f78);  // vmcnt(8)
    else    __builtin_amdgcn_s_waitcnt(0x0f70);  // tail vmcnt(0)
    __builtin_amdgcn_s_barrier();
    // ---- phase 2: A-hi reads; MFMA mhi*nhi ----
#pragma unroll
    for (int mt = 0; mt < 4; ++mt)
#pragma unroll
      for (int ks = 0; ks < 2; ++ks) a[mt * 2 + ks] = ldA(t, mt + 4, ks);
    __builtin_amdgcn_s_barrier();
    wait_lds();
    __builtin_amdgcn_s_setprio(1);
#pragma unroll
    for (int mt = 0; mt < 4; ++mt)
#pragma unroll
      for (int nt = 0; nt < 2; ++nt)
#pragma unroll
        for (int ks = 0; ks < 2; ++ks)
          acc[mt + 4][nt + 2] = __builtin_amdgcn_mfma_f32_16x16x32_bf16(a[mt * 2 + ks], b1[nt * 2 + ks], acc[mt + 4][nt + 2], 0, 0, 0);
    __builtin_amdgcn_s_setprio(0);
    __builtin_amdgcn_s_barrier();
    // ---- phase 3: no reads/stages; MFMA mhi*nlo (b0 held since ph0) ----
    __builtin_amdgcn_s_setprio(1);
#pragma unroll
    for (int mt = 0; mt < 4; ++mt)
#pragma unroll
      for (int nt = 0; nt < 2; ++nt)
#pragma unroll
        for (int ks = 0; ks < 2; ++ks)
          acc[mt + 4][nt] = __builtin_amdgcn_mfma_f32_16x16x32_bf16(a[mt * 2 + ks], b0[nt * 2 + ks], acc[mt + 4][nt], 0, 0, 0);
    __builtin_amdgcn_s_setprio(0);
    // next tile's gate barrier bounds ph3
  }

  __syncthreads();  // quiesce before LDS reuse by epilogue

  if (OUT_F32) {
#pragma unroll
    for (int nt = 0; nt < 4; ++nt) {
      long coln = n0 + wn * 64 + nt * 16 + ln;
      float bv = bias[coln];
#pragma unroll
      for (int mt = 0; mt < 8; ++mt) {
        long rowb = m0 + wm * 128 + mt * 16 + quad * 4;
#pragma unroll
        for (int r = 0; r < 4; ++r)
          ((float*)Cv)[(rowb + r) * N + coln] = acc[mt][nt][r] + bv;
      }
    }
  } else {
    // bf16: wave-private LDS patch for full-line 16B stores
    u16* patch = &lds[wave * 2176];  // [16][136]
    float bv[4];
#pragma unroll
    for (int nt = 0; nt < 4; ++nt) bv[nt] = bias[n0 + wn * 64 + nt * 16 + ln];
#pragma unroll
    for (int mt = 0; mt < 8; ++mt) {
#pragma unroll
      for (int nt = 0; nt < 4; ++nt)
#pragma unroll
        for (int r = 0; r < 4; ++r)
          patch[(quad * 4 + r) * 136 + nt * 16 + ln] = f2b(acc[mt][nt][r] + bv[nt]);
      wait_lds();  // cross-lane LDS RAW
#pragma unroll
      for (int it = 0; it < 2; ++it) {
        int cid = it * 64 + lane;
        int row = cid >> 3, ch = cid & 7;
        uint4 v = *(const uint4*)&patch[row * 136 + ch * 8];
        *(uint4*)&((u16*)Cv)[(m0 + wm * 128 + mt * 16 + row) * (long)N + n0 + wn * 64 + ch * 8] = v;
      }
      wait_lds();  // patch reads retired before next mt overwrites
    }
  }
}

// ---------------- fused attention per (n, head) ----------------
// qkv row layout [1536]: head h cols [h*192, +192) = q|k|v of 64.
// Block = 4 waves; wave w, strip s handles q-rows [w*64+s*32, +32).
// LDS: Ks [256][64] + Vt [64][256] = 64 KB; P aliases Ks during PV (waves
// are locksteppped by __syncthreads; K re-staged between strips).
__global__ __launch_bounds__(256, 2) void attn_fused(const u16* __restrict__ qkv,
                                                     u16* __restrict__ out) {
  __shared__ alignas(16) u16 Ks[256 * 64];  // [j][64], 16B chunk c stored at c^(j&7)
  __shared__ alignas(16) u16 Vt[64 * 256];  // [d][256], chunk cj stored at cj^(((d>>3)^d)&7)
  const int h = blockIdx.x;
  const long n = blockIdx.y;
  const int tid = threadIdx.x;
  const int lane = tid & 63, wave = tid >> 6;
  const int quad = lane >> 4, ln = lane & 15;
  const u16* base = qkv + (n * 256) * 1536 + h * 192;

  // ---- stage K (coalesced 16B loads; swizzled 16B LDS writes, conflict-free) ----
  auto stageK = [&]() {
    int c = tid & 7, jb = tid >> 3;
#pragma unroll
    for (int rr = 0; rr < 8; ++rr) {
      int j = jb + rr * 32;
      uint4 v = *(const uint4*)(base + (long)j * 1536 + 64 + c * 8);
      *(uint4*)&Ks[j * 64 + ((c ^ (j & 7)) * 8)] = v;
    }
  };
  stageK();
  // ---- stage V^T (coalesced loads; scalar scatter, key=(p^i) -> conflict-free) ----
  {
    int p = tid & 7, jb = tid >> 3;
#pragma unroll
    for (int rr = 0; rr < 8; ++rr) {
      int j = jb + rr * 32;
      union { uint4 v; u16 e[8]; } u;
      u.v = *(const uint4*)(base + (long)j * 1536 + 128 + p * 8);
      int cj = j >> 3, jl = j & 7;
#pragma unroll
      for (int i = 0; i < 8; ++i) {
        int d = p * 8 + i;
        int key = (p ^ i) & 7;  // == ((d>>3)^d)&7
        Vt[d * 256 + ((cj ^ key) * 8) + jl] = u.e[i];
      }
    }
  }
  __syncthreads();

  u16* Pw = &Ks[wave * 2176];  // [16][136] u16, aliases Ks during PV phases
  f32x4 zero = {0.f, 0.f, 0.f, 0.f};

  for (int s = 0; s < 2; ++s) {
    const int row0 = wave * 64 + s * 32;
    // q A-frags from global (rows x 64B lines, read once — coalesced)
    bf16x8 qa[2][2];
#pragma unroll
    for (int mt = 0; mt < 2; ++mt)
#pragma unroll
      for (int kc = 0; kc < 2; ++kc)
        qa[mt][kc] = ld_frag(base + (long)(row0 + mt * 16 + ln) * 1536 + kc * 32 + quad * 8);

    f32x4 sacc[2][16];
#pragma unroll
    for (int mt = 0; mt < 2; ++mt)
#pragma unroll
      for (int jt = 0; jt < 16; ++jt) sacc[mt][jt] = zero;

    // S = q k^T, kb from swizzled LDS
#pragma unroll
    for (int jt = 0; jt < 16; ++jt) {
#pragma unroll
      for (int kc = 0; kc < 2; ++kc) {
        bf16x8 kb = ld_frag(&Ks[(jt * 16 + ln) * 64 + (((kc * 4 + quad) ^ (ln & 7)) * 8)]);
        sacc[0][jt] = __builtin_amdgcn_mfma_f32_16x16x32_bf16(qa[0][kc], kb, sacc[0][jt], 0, 0, 0);
        sacc[1][jt] = __builtin_amdgcn_mfma_f32_16x16x32_bf16(qa[1][kc], kb, sacc[1][jt], 0, 0, 0);
      }
    }
    __syncthreads();  // all waves done reading Ks -> P may alias it

#pragma unroll
    for (int mt = 0; mt < 2; ++mt) {
      // softmax over j (rows at quad*4+r, cols at jt*16+ln)
      float linv[4];
#pragma unroll
      for (int r = 0; r < 4; ++r) {
        float mx = -3.0e38f;
#pragma unroll
        for (int jt = 0; jt < 16; ++jt) mx = fmaxf(mx, sacc[mt][jt][r]);
        mx = fmaxf(mx, __shfl_xor(mx, 1));
        mx = fmaxf(mx, __shfl_xor(mx, 2));
        mx = fmaxf(mx, __shfl_xor(mx, 4));
        mx = fmaxf(mx, __shfl_xor(mx, 8));
        float l = 0.f;
#pragma unroll
        for (int jt = 0; jt < 16; ++jt) {
          float p = __expf((sacc[mt][jt][r] - mx) * 0.125f);  // 1/sqrt(dh)
          sacc[mt][jt][r] = p;
          l += p;
        }
        l += __shfl_xor(l, 1);
        l += __shfl_xor(l, 2);
        l += __shfl_xor(l, 4);
        l += __shfl_xor(l, 8);
        linv[r] = 1.0f / l;
      }

      // O = P V in two j-halves of 128 (P buffer reused; oacc accumulates)
      f32x4 oacc[4];
#pragma unroll
      for (int dt = 0; dt < 4; ++dt) oacc[dt] = zero;
#pragma unroll
      for (int jh = 0; jh < 2; ++jh) {
#pragma unroll
        for (int jl = 0; jl < 8; ++jl) {
          int jt = jh * 8 + jl;
#pragma unroll
          for (int r = 0; r < 4; ++r)
            Pw[(quad * 4 + r) * 136 + jl * 16 + ln] = f2b(sacc[mt][jt][r]);
        }
        wait_lds();  // cross-lane LDS RAW
#pragma unroll
        for (int jcl = 0; jcl < 4; ++jcl) {
          bf16x8 pa = ld_frag(&Pw[ln * 136 + jcl * 32 + quad * 8]);
          int cjb = (jh * 4 + jcl) * 4 + quad;
#pragma unroll
          for (int dt = 0; dt < 4; ++dt) {
            int d = dt * 16 + ln;
            int key = ((d >> 3) ^ d) & 7;
            bf16x8 vb = ld_frag(&Vt[d * 256 + ((cjb ^ key) * 8)]);
            oacc[dt] = __builtin_amdgcn_mfma_f32_16x16x32_bf16(pa, vb, oacc[dt], 0, 0, 0);
          }
        }
      }
      // stage O tile (16 x 64) into Pw, then coalesced 16B global stores
#pragma unroll
      for (int dt = 0; dt < 4; ++dt)
#pragma unroll
        for (int r = 0; r < 4; ++r)
          Pw[(quad * 4 + r) * 136 + dt * 16 + ln] = f2b(oacc[dt][r] * linv[r]);
      wait_lds();
#pragma unroll
      for (int it = 0; it < 2; ++it) {
        int cid = it * 64 + lane;
        int row = cid >> 3, ch = cid & 7;
        uint4 v = *(const uint4*)&Pw[row * 136 + ch * 8];
        *(uint4*)&out[(n * 256 + row0 + mt * 16 + row) * 512 + h * 64 + ch * 8] = v;
      }
    }
    __syncthreads();  // P region quiesced
    if (s == 0) {
      stageK();       // restore K for strip 1
      __syncthreads();
    }
  }
}

extern "C" void kernel_launch(void* const* d_in, const int* in_sizes, int n_in,
                              void* d_out, int out_size, void* d_ws, size_t ws_size,
                              hipStream_t stream) {
  const float* x      = (const float*)d_in[0];  // [65536][512] fp32
  const float* w_qkv  = (const float*)d_in[1];  // [512][1536]
  const float* b_qkv  = (const float*)d_in[2];  // [1536]
  const float* w_proj = (const float*)d_in[3];  // [512][512]
  const float* b_proj = (const float*)d_in[4];  // [512]
  float* out = (float*)d_out;                   // [65536][512] fp32

  char* ws = (char*)d_ws;
  u16* xb   = (u16*)ws;                                         // 64 MiB
  u16* qkv  = (u16*)(ws + 67108864L);                           // 192 MiB
  u16* attn = (u16*)(ws + 67108864L + 201326592L);              // 64 MiB
  u16* Wt1  = (u16*)(ws + 67108864L + 201326592L + 67108864L);  // 1536x512
  u16* Wt2  = Wt1 + 1536 * 512;                                 // 512x512

  convert_f32_bf16<<<16384, 256, 0, stream>>>(x, xb);
  transpose_w<<<dim3(24, 8), 256, 0, stream>>>(w_qkv, Wt1, 512, 1536);
  transpose_w<<<dim3(8, 8), 256, 0, stream>>>(w_proj, Wt2, 512, 512);
  // grids: (M/256)*(N/256) blocks, both % 8 == 0 (bijective XCD swizzle)
  gemm_pipe<false><<<dim3(6 * 256), 512, 0, stream>>>(xb, Wt1, b_qkv, qkv, 65536, 1536, 512);
  attn_fused<<<dim3(8, 256), 256, 0, stream>>>(qkv, attn);
  gemm_pipe<true><<<dim3(2 * 256), 512, 0, stream>>>(attn, Wt2, b_proj, out, 65536, 512, 512);
}

// Round 9
// 543.135 us; speedup vs baseline: 1.0204x; 1.0204x over previous
//
#include <hip/hip_runtime.h>

typedef unsigned short u16;
typedef unsigned int u32;
typedef __bf16 bf16x8 __attribute__((ext_vector_type(8)));
typedef float f32x4 __attribute__((ext_vector_type(4)));

__device__ __forceinline__ u16 f2b(float f) {
  u32 u = __builtin_bit_cast(u32, f);
  u32 r = (u + 0x7fffu + ((u >> 16) & 1u)) >> 16;  // RNE
  return (u16)r;
}
__device__ __forceinline__ bf16x8 ld_frag(const u16* p) {
  uint4 v = *(const uint4*)p;
  return __builtin_bit_cast(bf16x8, v);
}
__device__ __forceinline__ void async_lds16(const u16* g, u16* lds) {
  __builtin_amdgcn_global_load_lds(
      (const __attribute__((address_space(1))) void*)g,
      (__attribute__((address_space(3))) void*)lds, 16, 0, 0);
}
// wait lgkmcnt(0) only (vmcnt=63, expcnt=7 untouched)
__device__ __forceinline__ void wait_lds() { __builtin_amdgcn_s_waitcnt(0xc07f); }

// ---------------- fp32 -> bf16 bulk convert (x) ----------------
__global__ __launch_bounds__(256) void convert_f32_bf16(const float* __restrict__ in,
                                                        u16* __restrict__ out) {
  long i = ((long)blockIdx.x * 256 + threadIdx.x) * 8;
  float4 a = *(const float4*)(in + i);
  float4 b = *(const float4*)(in + i + 4);
  union { uint4 v; u16 e[8]; } u;
  u.e[0] = f2b(a.x); u.e[1] = f2b(a.y); u.e[2] = f2b(a.z); u.e[3] = f2b(a.w);
  u.e[4] = f2b(b.x); u.e[5] = f2b(b.y); u.e[6] = f2b(b.z); u.e[7] = f2b(b.w);
  *(uint4*)(out + i) = u.v;
}

// ---------------- weight transpose+convert: W_f32[K][N] -> Wt_bf16[N][K] ----------------
__global__ __launch_bounds__(256) void transpose_w(const float* __restrict__ W,
                                                   u16* __restrict__ Wt,
                                                   int K, int N) {
  __shared__ alignas(16) u16 T[64][80];
  const int n0 = blockIdx.x * 64, k0 = blockIdx.y * 64;
  const int t = threadIdx.x;
  {
    int kk = t >> 3, c = t & 7;
#pragma unroll
    for (int rr = 0; rr < 2; ++rr) {
      int kr = kk + rr * 32;
      const float* src = W + (long)(k0 + kr) * N + n0 + c * 8;
      float4 a = *(const float4*)src;
      float4 b = *(const float4*)(src + 4);
      u16* dst = &T[kr][c * 8];
      dst[0] = f2b(a.x); dst[1] = f2b(a.y); dst[2] = f2b(a.z); dst[3] = f2b(a.w);
      dst[4] = f2b(b.x); dst[5] = f2b(b.y); dst[6] = f2b(b.z); dst[7] = f2b(b.w);
    }
  }
  __syncthreads();
  {
    int nn = t >> 3, kc = t & 7;
#pragma unroll
    for (int rr = 0; rr < 2; ++rr) {
      int nr = nn + rr * 32;
      union { uint4 v; u16 e[8]; } u;
#pragma unroll
      for (int i = 0; i < 8; ++i) u.e[i] = T[kc * 8 + i][nr];
      *(uint4*)(Wt + (long)(n0 + nr) * K + k0 + kc * 8) = u.v;
    }
  }
}

// ---------------- 2-block/CU pipelined GEMM: C = A_bf16[M][K] * Bt_bf16[N][K]^T + bias ----------
// BM=256 BN=128 BK=32; 512 thr = 8 waves (4M x 2N), wave tile 64x64 (acc[4][4]=64 VGPR).
// __launch_bounds__(512,4): VGPR capped at 128 -> with 72 KiB LDS/block -> 2 blocks/CU,
// 4 waves/SIMD. Cross-BLOCK overlap hides barrier/sync slack (the round-8 structure was
// 1 block/CU lockstep: MfmaUtil 29%).
// LDS ring-3: slot (t%3) = 24 KiB {A unit0 rows0-127 @0, A unit1 rows128-255 @8KiB,
// B rows0-127 @16KiB}. Stage t+2 during tile t (3 x global_load_lds of 8 KiB).
// ONE barrier per K-tile. Counted gate: vmcnt(3) -> tile t's 3 stages landed, tile
// t+1's 3 still in flight (never 0 mid-loop; tail vmcnt(0) drains 2-tile-old loads).
// Race-freedom: stages(t) write slot (t+2)%3 == slot(t-1); every wave's reads of that
// slot were lgkm-drained (wait_lds before MFMA in t-1) before it passed barrier(t),
// and stages issue after barrier(t) -> no write-before-read.
// Swizzle (64B rows): pair rows per 128B line; 16B slot s' = ((q<<1)|(r&1)) ^ ((r>>1)&7).
// Read banks: per 16-lane group every slot hit exactly 2x -> 2 lanes/bank = free (m136).
// Staged with linear LDS dest + inverse-mapped global source (thread tid -> line R=tid>>3,
// slot sp=tid&7 -> logical sl=sp^(R&7) -> row (R<<1)|(sl&1), col (sl>>1)*8).
template <bool OUT_F32>
__global__ __launch_bounds__(512, 4) void gemm_pipe(const u16* __restrict__ A,
                                                    const u16* __restrict__ Bt,
                                                    const float* __restrict__ bias,
                                                    void* __restrict__ Cv,
                                                    int M, int N, int K) {
  __shared__ alignas(16) u16 lds[3 * 12288];  // 3 x 24 KiB
  const int tid = threadIdx.x;
  const int lane = tid & 63, wave = tid >> 6;
  const int quad = lane >> 4, ln = lane & 15;
  const int wm = wave >> 1, wn = wave & 1;  // per-wave 64x64 tile

  // XCD-aware bijective swizzle (nwg % 8 == 0 for both launches)
  const int nwg = gridDim.x;
  const int bid = blockIdx.x;
  const int wg = (bid & 7) * (nwg >> 3) + (bid >> 3);
  const int ntn = N >> 7;
  const int tn = wg % ntn, tm = wg / ntn;
  const long m0 = (long)tm * 256;
  const long n0 = (long)tn * 128;

  // staging source (inverse of read swizzle); one gload_lds = 512thr x 16B = 8 KiB unit
  const int R = tid >> 3, sp = tid & 7;
  const int sl = sp ^ (R & 7);
  const int sru = (R << 1) | (sl & 1);   // row within 128-row unit
  const int scol = (sl >> 1) * 8;        // element col within 32-elem row
  const u16* gA0 = A + (m0 + sru) * (long)K + scol;
  const u16* gA1 = A + (m0 + 128 + sru) * (long)K + scol;
  const u16* gB0 = Bt + (n0 + sru) * (long)K + scol;

  const int KT = K >> 5;

  auto stage = [&](int t) {
    if (t >= KT) return;
    long ko = (long)t * 32;
    u16* s = &lds[(t % 3) * 12288 + wave * 512];
    async_lds16(gA0 + ko, s);
    async_lds16(gA1 + ko, s + 4096);
    async_lds16(gB0 + ko, s + 8192);
  };

  auto ldA = [&](int t, int mt) {
    int ra = wm * 64 + mt * 16 + ln;            // 0..255
    int u = ra >> 7, ru = ra & 127, Rr = ru >> 1;
    int s2 = ((quad << 1) | (ru & 1)) ^ (Rr & 7);
    return ld_frag(&lds[(t % 3) * 12288 + u * 4096 + Rr * 64 + s2 * 8]);
  };
  auto ldB = [&](int t, int nt) {
    int rb = wn * 64 + nt * 16 + ln;            // 0..127
    int Rr = rb >> 1;
    int s2 = ((quad << 1) | (rb & 1)) ^ (Rr & 7);
    return ld_frag(&lds[(t % 3) * 12288 + 8192 + Rr * 64 + s2 * 8]);
  };

  f32x4 zero = {0.f, 0.f, 0.f, 0.f};
  f32x4 acc[4][4];
#pragma unroll
  for (int i = 0; i < 4; ++i)
#pragma unroll
    for (int j = 0; j < 4; ++j) acc[i][j] = zero;

  // prologue: stage tiles 0,1 (6 loads in flight)
  stage(0); stage(1);

  for (int t = 0; t < KT; ++t) {
    // gate: tile t landed (t+1's 3 stay in flight). Literal-constant waitcnts.
    if (t < KT - 1) __builtin_amdgcn_s_waitcnt(0x0f73);  // vmcnt(3)
    else            __builtin_amdgcn_s_waitcnt(0x0f70);  // tail vmcnt(0)
    __builtin_amdgcn_s_barrier();
    stage(t + 2);  // writes slot(t-1): safe (see header)
    bf16x8 a[4], b[4];
#pragma unroll
    for (int mt = 0; mt < 4; ++mt) a[mt] = ldA(t, mt);
#pragma unroll
    for (int nt = 0; nt < 4; ++nt) b[nt] = ldB(t, nt);
    wait_lds();  // own 8 ds_reads complete (cross-lane MFMA operands)
    __builtin_amdgcn_s_setprio(1);
#pragma unroll
    for (int mt = 0; mt < 4; ++mt)
#pragma unroll
      for (int nt = 0; nt < 4; ++nt)
        acc[mt][nt] = __builtin_amdgcn_mfma_f32_16x16x32_bf16(a[mt], b[nt], acc[mt][nt], 0, 0, 0);
    __builtin_amdgcn_s_setprio(0);
  }

  __syncthreads();  // quiesce before LDS reuse by epilogue

  if (OUT_F32) {
#pragma unroll
    for (int nt = 0; nt < 4; ++nt) {
      long coln = n0 + wn * 64 + nt * 16 + ln;
      float bv = bias[coln];
#pragma unroll
      for (int mt = 0; mt < 4; ++mt) {
        long rowb = m0 + wm * 64 + mt * 16 + quad * 4;
#pragma unroll
        for (int r = 0; r < 4; ++r)
          ((float*)Cv)[(rowb + r) * N + coln] = acc[mt][nt][r] + bv;
      }
    }
  } else {
    // bf16: wave-private LDS patch for full-line 16B stores
    u16* patch = &lds[wave * 2176];  // [16][136]
    float bv[4];
#pragma unroll
    for (int nt = 0; nt < 4; ++nt) bv[nt] = bias[n0 + wn * 64 + nt * 16 + ln];
#pragma unroll
    for (int mt = 0; mt < 4; ++mt) {
#pragma unroll
      for (int nt = 0; nt < 4; ++nt)
#pragma unroll
        for (int r = 0; r < 4; ++r)
          patch[(quad * 4 + r) * 136 + nt * 16 + ln] = f2b(acc[mt][nt][r] + bv[nt]);
      wait_lds();  // cross-lane LDS RAW
#pragma unroll
      for (int it = 0; it < 2; ++it) {
        int cid = it * 64 + lane;
        int row = cid >> 3, ch = cid & 7;
        uint4 v = *(const uint4*)&patch[row * 136 + ch * 8];
        *(uint4*)&((u16*)Cv)[(m0 + wm * 64 + mt * 16 + row) * (long)N + n0 + wn * 64 + ch * 8] = v;
      }
      wait_lds();  // patch reads retired before next mt overwrites
    }
  }
}

// ---------------- fused attention per (n, head) ----------------
// qkv row layout [1536]: head h cols [h*192, +192) = q|k|v of 64.
// Block = 4 waves; wave w, strip s handles q-rows [w*64+s*32, +32).
// LDS: Ks [256][64] + Vt [64][256] = 64 KB; P aliases Ks during PV (waves
// are locksteppped by __syncthreads; K re-staged between strips).
__global__ __launch_bounds__(256, 2) void attn_fused(const u16* __restrict__ qkv,
                                                     u16* __restrict__ out) {
  __shared__ alignas(16) u16 Ks[256 * 64];  // [j][64], 16B chunk c stored at c^(j&7)
  __shared__ alignas(16) u16 Vt[64 * 256];  // [d][256], chunk cj stored at cj^(((d>>3)^d)&7)
  const int h = blockIdx.x;
  const long n = blockIdx.y;
  const int tid = threadIdx.x;
  const int lane = tid & 63, wave = tid >> 6;
  const int quad = lane >> 4, ln = lane & 15;
  const u16* base = qkv + (n * 256) * 1536 + h * 192;

  // ---- stage K (coalesced 16B loads; swizzled 16B LDS writes, conflict-free) ----
  auto stageK = [&]() {
    int c = tid & 7, jb = tid >> 3;
#pragma unroll
    for (int rr = 0; rr < 8; ++rr) {
      int j = jb + rr * 32;
      uint4 v = *(const uint4*)(base + (long)j * 1536 + 64 + c * 8);
      *(uint4*)&Ks[j * 64 + ((c ^ (j & 7)) * 8)] = v;
    }
  };
  stageK();
  // ---- stage V^T (coalesced loads; scalar scatter, key=(p^i) -> conflict-free) ----
  {
    int p = tid & 7, jb = tid >> 3;
#pragma unroll
    for (int rr = 0; rr < 8; ++rr) {
      int j = jb + rr * 32;
      union { uint4 v; u16 e[8]; } u;
      u.v = *(const uint4*)(base + (long)j * 1536 + 128 + p * 8);
      int cj = j >> 3, jl = j & 7;
#pragma unroll
      for (int i = 0; i < 8; ++i) {
        int d = p * 8 + i;
        int key = (p ^ i) & 7;  // == ((d>>3)^d)&7
        Vt[d * 256 + ((cj ^ key) * 8) + jl] = u.e[i];
      }
    }
  }
  __syncthreads();

  u16* Pw = &Ks[wave * 2176];  // [16][136] u16, aliases Ks during PV phases
  f32x4 zero = {0.f, 0.f, 0.f, 0.f};

  for (int s = 0; s < 2; ++s) {
    const int row0 = wave * 64 + s * 32;
    // q A-frags from global (rows x 64B lines, read once — coalesced)
    bf16x8 qa[2][2];
#pragma unroll
    for (int mt = 0; mt < 2; ++mt)
#pragma unroll
      for (int kc = 0; kc < 2; ++kc)
        qa[mt][kc] = ld_frag(base + (long)(row0 + mt * 16 + ln) * 1536 + kc * 32 + quad * 8);

    f32x4 sacc[2][16];
#pragma unroll
    for (int mt = 0; mt < 2; ++mt)
#pragma unroll
      for (int jt = 0; jt < 16; ++jt) sacc[mt][jt] = zero;

    // S = q k^T, kb from swizzled LDS
#pragma unroll
    for (int jt = 0; jt < 16; ++jt) {
#pragma unroll
      for (int kc = 0; kc < 2; ++kc) {
        bf16x8 kb = ld_frag(&Ks[(jt * 16 + ln) * 64 + (((kc * 4 + quad) ^ (ln & 7)) * 8)]);
        sacc[0][jt] = __builtin_amdgcn_mfma_f32_16x16x32_bf16(qa[0][kc], kb, sacc[0][jt], 0, 0, 0);
        sacc[1][jt] = __builtin_amdgcn_mfma_f32_16x16x32_bf16(qa[1][kc], kb, sacc[1][jt], 0, 0, 0);
      }
    }
    __syncthreads();  // all waves done reading Ks -> P may alias it

#pragma unroll
    for (int mt = 0; mt < 2; ++mt) {
      // softmax over j (rows at quad*4+r, cols at jt*16+ln)
      float linv[4];
#pragma unroll
      for (int r = 0; r < 4; ++r) {
        float mx = -3.0e38f;
#pragma unroll
        for (int jt = 0; jt < 16; ++jt) mx = fmaxf(mx, sacc[mt][jt][r]);
        mx = fmaxf(mx, __shfl_xor(mx, 1));
        mx = fmaxf(mx, __shfl_xor(mx, 2));
        mx = fmaxf(mx, __shfl_xor(mx, 4));
        mx = fmaxf(mx, __shfl_xor(mx, 8));
        float l = 0.f;
#pragma unroll
        for (int jt = 0; jt < 16; ++jt) {
          float p = __expf((sacc[mt][jt][r] - mx) * 0.125f);  // 1/sqrt(dh)
          sacc[mt][jt][r] = p;
          l += p;
        }
        l += __shfl_xor(l, 1);
        l += __shfl_xor(l, 2);
        l += __shfl_xor(l, 4);
        l += __shfl_xor(l, 8);
        linv[r] = 1.0f / l;
      }

      // O = P V in two j-halves of 128 (P buffer reused; oacc accumulates)
      f32x4 oacc[4];
#pragma unroll
      for (int dt = 0; dt < 4; ++dt) oacc[dt] = zero;
#pragma unroll
      for (int jh = 0; jh < 2; ++jh) {
#pragma unroll
        for (int jl = 0; jl < 8; ++jl) {
          int jt = jh * 8 + jl;
#pragma unroll
          for (int r = 0; r < 4; ++r)
            Pw[(quad * 4 + r) * 136 + jl * 16 + ln] = f2b(sacc[mt][jt][r]);
        }
        wait_lds();  // cross-lane LDS RAW
#pragma unroll
        for (int jcl = 0; jcl < 4; ++jcl) {
          bf16x8 pa = ld_frag(&Pw[ln * 136 + jcl * 32 + quad * 8]);
          int cjb = (jh * 4 + jcl) * 4 + quad;
#pragma unroll
          for (int dt = 0; dt < 4; ++dt) {
            int d = dt * 16 + ln;
            int key = ((d >> 3) ^ d) & 7;
            bf16x8 vb = ld_frag(&Vt[d * 256 + ((cjb ^ key) * 8)]);
            oacc[dt] = __builtin_amdgcn_mfma_f32_16x16x32_bf16(pa, vb, oacc[dt], 0, 0, 0);
          }
        }
      }
      // stage O tile (16 x 64) into Pw, then coalesced 16B global stores
#pragma unroll
      for (int dt = 0; dt < 4; ++dt)
#pragma unroll
        for (int r = 0; r < 4; ++r)
          Pw[(quad * 4 + r) * 136 + dt * 16 + ln] = f2b(oacc[dt][r] * linv[r]);
      wait_lds();
#pragma unroll
      for (int it = 0; it < 2; ++it) {
        int cid = it * 64 + lane;
        int row = cid >> 3, ch = cid & 7;
        uint4 v = *(const uint4*)&Pw[row * 136 + ch * 8];
        *(uint4*)&out[(n * 256 + row0 + mt * 16 + row) * 512 + h * 64 + ch * 8] = v;
      }
    }
    __syncthreads();  // P region quiesced
    if (s == 0) {
      stageK();       // restore K for strip 1
      __syncthreads();
    }
  }
}

extern "C" void kernel_launch(void* const* d_in, const int* in_sizes, int n_in,
                              void* d_out, int out_size, void* d_ws, size_t ws_size,
                              hipStream_t stream) {
  const float* x      = (const float*)d_in[0];  // [65536][512] fp32
  const float* w_qkv  = (const float*)d_in[1];  // [512][1536]
  const float* b_qkv  = (const float*)d_in[2];  // [1536]
  const float* w_proj = (const float*)d_in[3];  // [512][512]
  const float* b_proj = (const float*)d_in[4];  // [512]
  float* out = (float*)d_out;                   // [65536][512] fp32

  char* ws = (char*)d_ws;
  u16* xb   = (u16*)ws;                                         // 64 MiB
  u16* qkv  = (u16*)(ws + 67108864L);                           // 192 MiB
  u16* attn = (u16*)(ws + 67108864L + 201326592L);              // 64 MiB
  u16* Wt1  = (u16*)(ws + 67108864L + 201326592L + 67108864L);  // 1536x512
  u16* Wt2  = Wt1 + 1536 * 512;                                 // 512x512

  convert_f32_bf16<<<16384, 256, 0, stream>>>(x, xb);
  transpose_w<<<dim3(24, 8), 256, 0, stream>>>(w_qkv, Wt1, 512, 1536);
  transpose_w<<<dim3(8, 8), 256, 0, stream>>>(w_proj, Wt2, 512, 512);
  // grids: (M/256)*(N/128) blocks: QKV 256*12=3072, proj 256*4=1024 (both %8==0)
  gemm_pipe<false><<<dim3(3072), 512, 0, stream>>>(xb, Wt1, b_qkv, qkv, 65536, 1536, 512);
  attn_fused<<<dim3(8, 256), 256, 0, stream>>>(qkv, attn);
  gemm_pipe<true><<<dim3(1024), 512, 0, stream>>>(attn, Wt2, b_proj, out, 65536, 512, 512);
}

// Round 10
// 537.344 us; speedup vs baseline: 1.0314x; 1.0108x over previous
//
#include <hip/hip_runtime.h>

typedef unsigned short u16;
typedef unsigned int u32;
typedef __bf16 bf16x8 __attribute__((ext_vector_type(8)));
typedef float f32x4 __attribute__((ext_vector_type(4)));

__device__ __forceinline__ u16 f2b(float f) {
  u32 u = __builtin_bit_cast(u32, f);
  u32 r = (u + 0x7fffu + ((u >> 16) & 1u)) >> 16;  // RNE
  return (u16)r;
}
__device__ __forceinline__ bf16x8 ld_frag(const u16* p) {
  uint4 v = *(const uint4*)p;
  return __builtin_bit_cast(bf16x8, v);
}
__device__ __forceinline__ void async_lds16(const u16* g, u16* lds) {
  __builtin_amdgcn_global_load_lds(
      (const __attribute__((address_space(1))) void*)g,
      (__attribute__((address_space(3))) void*)lds, 16, 0, 0);
}
// wait lgkmcnt(0) only (vmcnt=63, expcnt=7 untouched)
__device__ __forceinline__ void wait_lds() { __builtin_amdgcn_s_waitcnt(0xc07f); }

// ---------------- fp32 -> bf16 bulk convert (x) ----------------
__global__ __launch_bounds__(256) void convert_f32_bf16(const float* __restrict__ in,
                                                        u16* __restrict__ out) {
  long i = ((long)blockIdx.x * 256 + threadIdx.x) * 8;
  float4 a = *(const float4*)(in + i);
  float4 b = *(const float4*)(in + i + 4);
  union { uint4 v; u16 e[8]; } u;
  u.e[0] = f2b(a.x); u.e[1] = f2b(a.y); u.e[2] = f2b(a.z); u.e[3] = f2b(a.w);
  u.e[4] = f2b(b.x); u.e[5] = f2b(b.y); u.e[6] = f2b(b.z); u.e[7] = f2b(b.w);
  *(uint4*)(out + i) = u.v;
}

// ---------------- weight transpose+convert: W_f32[K][N] -> Wt_bf16[N][K] ----------------
__global__ __launch_bounds__(256) void transpose_w(const float* __restrict__ W,
                                                   u16* __restrict__ Wt,
                                                   int K, int N) {
  __shared__ alignas(16) u16 T[64][80];
  const int n0 = blockIdx.x * 64, k0 = blockIdx.y * 64;
  const int t = threadIdx.x;
  {
    int kk = t >> 3, c = t & 7;
#pragma unroll
    for (int rr = 0; rr < 2; ++rr) {
      int kr = kk + rr * 32;
      const float* src = W + (long)(k0 + kr) * N + n0 + c * 8;
      float4 a = *(const float4*)src;
      float4 b = *(const float4*)(src + 4);
      u16* dst = &T[kr][c * 8];
      dst[0] = f2b(a.x); dst[1] = f2b(a.y); dst[2] = f2b(a.z); dst[3] = f2b(a.w);
      dst[4] = f2b(b.x); dst[5] = f2b(b.y); dst[6] = f2b(b.z); dst[7] = f2b(b.w);
    }
  }
  __syncthreads();
  {
    int nn = t >> 3, kc = t & 7;
#pragma unroll
    for (int rr = 0; rr < 2; ++rr) {
      int nr = nn + rr * 32;
      union { uint4 v; u16 e[8]; } u;
#pragma unroll
      for (int i = 0; i < 8; ++i) u.e[i] = T[kc * 8 + i][nr];
      *(uint4*)(Wt + (long)(n0 + nr) * K + k0 + kc * 8) = u.v;
    }
  }
}

// ---------------- 2-block/CU pipelined GEMM: C = A_bf16[M][K] * Bt_bf16[N][K]^T + bias ----------
// BM=256 BN=128 BK=32; 512 thr = 8 waves (4M x 2N), wave tile 64x64 (acc[4][4]=64 VGPR).
// __launch_bounds__(512,4): VGPR capped at 128 -> with 72 KiB LDS/block -> 2 blocks/CU,
// 4 waves/SIMD. Cross-BLOCK overlap hides barrier/sync slack.
// LDS ring-3: slot (t%3) = 24 KiB {A unit0 rows0-127 @0, A unit1 rows128-255 @8KiB,
// B rows0-127 @16KiB}. Stage t+2 during tile t (3 x global_load_lds of 8 KiB).
// ONE barrier per K-tile. Counted gate: vmcnt(3) -> tile t's 3 stages landed, tile
// t+1's 3 still in flight (never 0 mid-loop; tail vmcnt(0) drains 1-tile-old loads).
// Race-freedom: stages(t) write slot (t+2)%3 == slot(t-1); every wave's reads of that
// slot were lgkm-drained (wait_lds before MFMA in t-1) before it passed barrier(t),
// and stages issue after barrier(t) -> no write-before-read.
// SWIZZLE (round-10 fix): ds_read_b128 sweeps 128B/cycle = 8 lanes/cycle-group;
// conflict-free requires each 8-lane subgroup to cover all 8 slots of a line once.
// Rows are 64B; pair rows (2R,2R+1) per 128B line. Slot of (row r, chunk quad q):
//   s = 2*(q ^ (line&3)) + (r&1),  line = r>>1.
// Fixed q, lanes 0..7 (rows base..base+7): s = 2*(q^{0..3}) + {0,1} = all 8 distinct. ✓
// Per line, (q, r&1) -> s is bijective. ✓ (Round-9's s=(2q|(r&1))^((r>>1)&7) packed
// duplicate slots inside 8-lane groups -> 1.4e7 conflicts, +4 cyc/read.)
// Staged linear-dest + inverse-mapped global source: thread tid -> line R=tid>>3,
// slot sp=tid&7 -> global row (R<<1)|(sp&1), chunk (sp>>1)^(R&3).
template <bool OUT_F32>
__global__ __launch_bounds__(512, 4) void gemm_pipe(const u16* __restrict__ A,
                                                    const u16* __restrict__ Bt,
                                                    const float* __restrict__ bias,
                                                    void* __restrict__ Cv,
                                                    int M, int N, int K) {
  __shared__ alignas(16) u16 lds[3 * 12288];  // 3 x 24 KiB
  const int tid = threadIdx.x;
  const int lane = tid & 63, wave = tid >> 6;
  const int quad = lane >> 4, ln = lane & 15;
  const int wm = wave >> 1, wn = wave & 1;  // per-wave 64x64 tile

  // XCD-aware bijective swizzle (nwg % 8 == 0 for both launches)
  const int nwg = gridDim.x;
  const int bid = blockIdx.x;
  const int wg = (bid & 7) * (nwg >> 3) + (bid >> 3);
  const int ntn = N >> 7;
  const int tn = wg % ntn, tm = wg / ntn;
  const long m0 = (long)tm * 256;
  const long n0 = (long)tn * 128;

  // staging source (inverse of read swizzle); one gload_lds = 512thr x 16B = 8 KiB unit
  const int R = tid >> 3, sp = tid & 7;
  const int sru = (R << 1) | (sp & 1);           // row within 128-row unit
  const int scol = ((sp >> 1) ^ (R & 3)) * 8;    // element col within 32-elem row
  const u16* gA0 = A + (m0 + sru) * (long)K + scol;
  const u16* gA1 = A + (m0 + 128 + sru) * (long)K + scol;
  const u16* gB0 = Bt + (n0 + sru) * (long)K + scol;

  const int KT = K >> 5;

  auto stage = [&](int t) {
    if (t >= KT) return;
    long ko = (long)t * 32;
    u16* s = &lds[(t % 3) * 12288 + wave * 512];
    async_lds16(gA0 + ko, s);
    async_lds16(gA1 + ko, s + 4096);
    async_lds16(gB0 + ko, s + 8192);
  };

  auto ldA = [&](int t, int mt) {
    int ra = wm * 64 + mt * 16 + ln;            // 0..255
    int u = ra >> 7, ru = ra & 127, Rr = ru >> 1;
    int s2 = ((quad ^ (Rr & 3)) << 1) | (ru & 1);
    return ld_frag(&lds[(t % 3) * 12288 + u * 4096 + Rr * 64 + s2 * 8]);
  };
  auto ldB = [&](int t, int nt) {
    int rb = wn * 64 + nt * 16 + ln;            // 0..127
    int Rr = rb >> 1;
    int s2 = ((quad ^ (Rr & 3)) << 1) | (rb & 1);
    return ld_frag(&lds[(t % 3) * 12288 + 8192 + Rr * 64 + s2 * 8]);
  };

  f32x4 zero = {0.f, 0.f, 0.f, 0.f};
  f32x4 acc[4][4];
#pragma unroll
  for (int i = 0; i < 4; ++i)
#pragma unroll
    for (int j = 0; j < 4; ++j) acc[i][j] = zero;

  // prologue: stage tiles 0,1 (6 loads in flight)
  stage(0); stage(1);

  for (int t = 0; t < KT; ++t) {
    // gate: tile t landed (t+1's 3 stay in flight). Literal-constant waitcnts.
    if (t < KT - 1) __builtin_amdgcn_s_waitcnt(0x0f73);  // vmcnt(3)
    else            __builtin_amdgcn_s_waitcnt(0x0f70);  // tail vmcnt(0)
    __builtin_amdgcn_s_barrier();
    stage(t + 2);  // writes slot(t-1): safe (see header)
    bf16x8 a[4], b[4];
#pragma unroll
    for (int mt = 0; mt < 4; ++mt) a[mt] = ldA(t, mt);
#pragma unroll
    for (int nt = 0; nt < 4; ++nt) b[nt] = ldB(t, nt);
    wait_lds();  // own 8 ds_reads complete (cross-lane MFMA operands)
    __builtin_amdgcn_s_setprio(1);
#pragma unroll
    for (int mt = 0; mt < 4; ++mt)
#pragma unroll
      for (int nt = 0; nt < 4; ++nt)
        acc[mt][nt] = __builtin_amdgcn_mfma_f32_16x16x32_bf16(a[mt], b[nt], acc[mt][nt], 0, 0, 0);
    __builtin_amdgcn_s_setprio(0);
  }

  __syncthreads();  // quiesce before LDS reuse by epilogue

  if (OUT_F32) {
#pragma unroll
    for (int nt = 0; nt < 4; ++nt) {
      long coln = n0 + wn * 64 + nt * 16 + ln;
      float bv = bias[coln];
#pragma unroll
      for (int mt = 0; mt < 4; ++mt) {
        long rowb = m0 + wm * 64 + mt * 16 + quad * 4;
#pragma unroll
        for (int r = 0; r < 4; ++r)
          ((float*)Cv)[(rowb + r) * N + coln] = acc[mt][nt][r] + bv;
      }
    }
  } else {
    // bf16: wave-private LDS patch for full-line 16B stores
    u16* patch = &lds[wave * 2176];  // [16][136]
    float bv[4];
#pragma unroll
    for (int nt = 0; nt < 4; ++nt) bv[nt] = bias[n0 + wn * 64 + nt * 16 + ln];
#pragma unroll
    for (int mt = 0; mt < 4; ++mt) {
#pragma unroll
      for (int nt = 0; nt < 4; ++nt)
#pragma unroll
        for (int r = 0; r < 4; ++r)
          patch[(quad * 4 + r) * 136 + nt * 16 + ln] = f2b(acc[mt][nt][r] + bv[nt]);
      wait_lds();  // cross-lane LDS RAW
#pragma unroll
      for (int it = 0; it < 2; ++it) {
        int cid = it * 64 + lane;
        int row = cid >> 3, ch = cid & 7;
        uint4 v = *(const uint4*)&patch[row * 136 + ch * 8];
        *(uint4*)&((u16*)Cv)[(m0 + wm * 64 + mt * 16 + row) * (long)N + n0 + wn * 64 + ch * 8] = v;
      }
      wait_lds();  // patch reads retired before next mt overwrites
    }
  }
}

// ---------------- fused attention per (n, head) ----------------
// qkv row layout [1536]: head h cols [h*192, +192) = q|k|v of 64.
// Block = 4 waves; wave w, strip s handles q-rows [w*64+s*32, +32).
// LDS: Ks [256][64] + Vt [64][256] = 64 KB; P aliases Ks during PV (waves
// are locksteppped by __syncthreads; K re-staged between strips).
__global__ __launch_bounds__(256, 2) void attn_fused(const u16* __restrict__ qkv,
                                                     u16* __restrict__ out) {
  __shared__ alignas(16) u16 Ks[256 * 64];  // [j][64], 16B chunk c stored at c^(j&7)
  __shared__ alignas(16) u16 Vt[64 * 256];  // [d][256], chunk cj stored at cj^(((d>>3)^d)&7)
  const int h = blockIdx.x;
  const long n = blockIdx.y;
  const int tid = threadIdx.x;
  const int lane = tid & 63, wave = tid >> 6;
  const int quad = lane >> 4, ln = lane & 15;
  const u16* base = qkv + (n * 256) * 1536 + h * 192;

  // ---- stage K (coalesced 16B loads; swizzled 16B LDS writes, conflict-free) ----
  auto stageK = [&]() {
    int c = tid & 7, jb = tid >> 3;
#pragma unroll
    for (int rr = 0; rr < 8; ++rr) {
      int j = jb + rr * 32;
      uint4 v = *(const uint4*)(base + (long)j * 1536 + 64 + c * 8);
      *(uint4*)&Ks[j * 64 + ((c ^ (j & 7)) * 8)] = v;
    }
  };
  stageK();
  // ---- stage V^T (coalesced loads; scalar scatter, key=(p^i) -> conflict-free) ----
  {
    int p = tid & 7, jb = tid >> 3;
#pragma unroll
    for (int rr = 0; rr < 8; ++rr) {
      int j = jb + rr * 32;
      union { uint4 v; u16 e[8]; } u;
      u.v = *(const uint4*)(base + (long)j * 1536 + 128 + p * 8);
      int cj = j >> 3, jl = j & 7;
#pragma unroll
      for (int i = 0; i < 8; ++i) {
        int d = p * 8 + i;
        int key = (p ^ i) & 7;  // == ((d>>3)^d)&7
        Vt[d * 256 + ((cj ^ key) * 8) + jl] = u.e[i];
      }
    }
  }
  __syncthreads();

  u16* Pw = &Ks[wave * 2176];  // [16][136] u16, aliases Ks during PV phases
  f32x4 zero = {0.f, 0.f, 0.f, 0.f};

  for (int s = 0; s < 2; ++s) {
    const int row0 = wave * 64 + s * 32;
    // q A-frags from global (rows x 64B lines, read once — coalesced)
    bf16x8 qa[2][2];
#pragma unroll
    for (int mt = 0; mt < 2; ++mt)
#pragma unroll
      for (int kc = 0; kc < 2; ++kc)
        qa[mt][kc] = ld_frag(base + (long)(row0 + mt * 16 + ln) * 1536 + kc * 32 + quad * 8);

    f32x4 sacc[2][16];
#pragma unroll
    for (int mt = 0; mt < 2; ++mt)
#pragma unroll
      for (int jt = 0; jt < 16; ++jt) sacc[mt][jt] = zero;

    // S = q k^T, kb from swizzled LDS
#pragma unroll
    for (int jt = 0; jt < 16; ++jt) {
#pragma unroll
      for (int kc = 0; kc < 2; ++kc) {
        bf16x8 kb = ld_frag(&Ks[(jt * 16 + ln) * 64 + (((kc * 4 + quad) ^ (ln & 7)) * 8)]);
        sacc[0][jt] = __builtin_amdgcn_mfma_f32_16x16x32_bf16(qa[0][kc], kb, sacc[0][jt], 0, 0, 0);
        sacc[1][jt] = __builtin_amdgcn_mfma_f32_16x16x32_bf16(qa[1][kc], kb, sacc[1][jt], 0, 0, 0);
      }
    }
    __syncthreads();  // all waves done reading Ks -> P may alias it

#pragma unroll
    for (int mt = 0; mt < 2; ++mt) {
      // softmax over j (rows at quad*4+r, cols at jt*16+ln)
      float linv[4];
#pragma unroll
      for (int r = 0; r < 4; ++r) {
        float mx = -3.0e38f;
#pragma unroll
        for (int jt = 0; jt < 16; ++jt) mx = fmaxf(mx, sacc[mt][jt][r]);
        mx = fmaxf(mx, __shfl_xor(mx, 1));
        mx = fmaxf(mx, __shfl_xor(mx, 2));
        mx = fmaxf(mx, __shfl_xor(mx, 4));
        mx = fmaxf(mx, __shfl_xor(mx, 8));
        float l = 0.f;
#pragma unroll
        for (int jt = 0; jt < 16; ++jt) {
          float p = __expf((sacc[mt][jt][r] - mx) * 0.125f);  // 1/sqrt(dh)
          sacc[mt][jt][r] = p;
          l += p;
        }
        l += __shfl_xor(l, 1);
        l += __shfl_xor(l, 2);
        l += __shfl_xor(l, 4);
        l += __shfl_xor(l, 8);
        linv[r] = 1.0f / l;
      }

      // O = P V in two j-halves of 128 (P buffer reused; oacc accumulates)
      f32x4 oacc[4];
#pragma unroll
      for (int dt = 0; dt < 4; ++dt) oacc[dt] = zero;
#pragma unroll
      for (int jh = 0; jh < 2; ++jh) {
#pragma unroll
        for (int jl = 0; jl < 8; ++jl) {
          int jt = jh * 8 + jl;
#pragma unroll
          for (int r = 0; r < 4; ++r)
            Pw[(quad * 4 + r) * 136 + jl * 16 + ln] = f2b(sacc[mt][jt][r]);
        }
        wait_lds();  // cross-lane LDS RAW
#pragma unroll
        for (int jcl = 0; jcl < 4; ++jcl) {
          bf16x8 pa = ld_frag(&Pw[ln * 136 + jcl * 32 + quad * 8]);
          int cjb = (jh * 4 + jcl) * 4 + quad;
#pragma unroll
          for (int dt = 0; dt < 4; ++dt) {
            int d = dt * 16 + ln;
            int key = ((d >> 3) ^ d) & 7;
            bf16x8 vb = ld_frag(&Vt[d * 256 + ((cjb ^ key) * 8)]);
            oacc[dt] = __builtin_amdgcn_mfma_f32_16x16x32_bf16(pa, vb, oacc[dt], 0, 0, 0);
          }
        }
      }
      // stage O tile (16 x 64) into Pw, then coalesced 16B global stores
#pragma unroll
      for (int dt = 0; dt < 4; ++dt)
#pragma unroll
        for (int r = 0; r < 4; ++r)
          Pw[(quad * 4 + r) * 136 + dt * 16 + ln] = f2b(oacc[dt][r] * linv[r]);
      wait_lds();
#pragma unroll
      for (int it = 0; it < 2; ++it) {
        int cid = it * 64 + lane;
        int row = cid >> 3, ch = cid & 7;
        uint4 v = *(const uint4*)&Pw[row * 136 + ch * 8];
        *(uint4*)&out[(n * 256 + row0 + mt * 16 + row) * 512 + h * 64 + ch * 8] = v;
      }
    }
    __syncthreads();  // P region quiesced
    if (s == 0) {
      stageK();       // restore K for strip 1
      __syncthreads();
    }
  }
}

extern "C" void kernel_launch(void* const* d_in, const int* in_sizes, int n_in,
                              void* d_out, int out_size, void* d_ws, size_t ws_size,
                              hipStream_t stream) {
  const float* x      = (const float*)d_in[0];  // [65536][512] fp32
  const float* w_qkv  = (const float*)d_in[1];  // [512][1536]
  const float* b_qkv  = (const float*)d_in[2];  // [1536]
  const float* w_proj = (const float*)d_in[3];  // [512][512]
  const float* b_proj = (const float*)d_in[4];  // [512]
  float* out = (float*)d_out;                   // [65536][512] fp32

  char* ws = (char*)d_ws;
  u16* xb   = (u16*)ws;                                         // 64 MiB
  u16* qkv  = (u16*)(ws + 67108864L);                           // 192 MiB
  u16* attn = (u16*)(ws + 67108864L + 201326592L);              // 64 MiB
  u16* Wt1  = (u16*)(ws + 67108864L + 201326592L + 67108864L);  // 1536x512
  u16* Wt2  = Wt1 + 1536 * 512;                                 // 512x512

  convert_f32_bf16<<<16384, 256, 0, stream>>>(x, xb);
  transpose_w<<<dim3(24, 8), 256, 0, stream>>>(w_qkv, Wt1, 512, 1536);
  transpose_w<<<dim3(8, 8), 256, 0, stream>>>(w_proj, Wt2, 512, 512);
  // grids: (M/256)*(N/128) blocks: QKV 256*12=3072, proj 256*4=1024 (both %8==0)
  gemm_pipe<false><<<dim3(3072), 512, 0, stream>>>(xb, Wt1, b_qkv, qkv, 65536, 1536, 512);
  attn_fused<<<dim3(8, 256), 256, 0, stream>>>(qkv, attn);
  gemm_pipe<true><<<dim3(1024), 512, 0, stream>>>(attn, Wt2, b_proj, out, 65536, 512, 512);
}